// Round 1
// baseline (429.676 us; speedup 1.0000x reference)
//
#include <hip/hip_runtime.h>
#include <math.h>

#define T_TOKENS 16384
#define NEXP 64
#define KDIM 4096
#define TM 32
#define KC 128
#define NK4 (KC / 4)          // 32
#define XS_STRIDE (KC + 4)    // 132 floats, multiple of 4 -> b128-aligned rows
#define WT_STRIDE NEXP        // wt[k][e], e contiguous

__global__ __launch_bounds__(256, 2) void topk_router_kernel(
    const float* __restrict__ x, const float* __restrict__ W,
    float* __restrict__ out)
{
    __shared__ float xs[TM * XS_STRIDE];        // 16.9 KB
    __shared__ float wt[KC * WT_STRIDE];        // 32 KB, transposed W chunk
    __shared__ float logits_s[TM * (NEXP + 1)]; // 8.3 KB

    const int tid = threadIdx.x;
    const int t0 = blockIdx.x * TM;

    // compute-tile mapping: 16 expert-groups x 16 token-groups
    const int eg  = tid & 15;   // expert group -> experts e0..e0+3
    const int tg  = tid >> 4;   // token group  -> tokens tt0, tt0+1
    const int e0  = eg * 4;
    const int tt0 = tg * 2;

    // W staging mapping: lane = expert
    const int we  = tid & 63;
    const int wkg = tid >> 6;   // 0..3 (wave id)

    float acc0[4], acc1[4];
    #pragma unroll
    for (int i = 0; i < 4; ++i) { acc0[i] = 0.f; acc1[i] = 0.f; }

    for (int kc0 = 0; kc0 < KDIM; kc0 += KC) {
        // ---- stage x tile: 32 tokens x 128 k, coalesced float4 loads ----
        #pragma unroll
        for (int m = 0; m < 4; ++m) {
            int idx = tid + m * 256;          // 0..1023 float4 slots
            int t   = idx >> 5;               // /32 (KC/4 float4 per row)
            int k4  = idx & 31;
            float4 v = *(const float4*)&x[(size_t)(t0 + t) * KDIM + kc0 + k4 * 4];
            *(float4*)&xs[t * XS_STRIDE + k4 * 4] = v;
        }
        // ---- stage W chunk transposed: wt[k][e] ----
        #pragma unroll
        for (int m = 0; m < 8; ++m) {
            int k = wkg * 32 + m * 4;         // 0..124
            float4 v = *(const float4*)&W[(size_t)we * KDIM + kc0 + k];
            wt[(k + 0) * WT_STRIDE + we] = v.x;
            wt[(k + 1) * WT_STRIDE + we] = v.y;
            wt[(k + 2) * WT_STRIDE + we] = v.z;
            wt[(k + 3) * WT_STRIDE + we] = v.w;
        }
        __syncthreads();

        // ---- inner: per k4, 6 b128 LDS reads + 32 FMAs ----
        #pragma unroll 4
        for (int k4 = 0; k4 < NK4; ++k4) {
            float xr0[4], xr1[4], wr[4][4];
            *(float4*)xr0 = *(const float4*)&xs[(tt0 + 0) * XS_STRIDE + 4 * k4];
            *(float4*)xr1 = *(const float4*)&xs[(tt0 + 1) * XS_STRIDE + 4 * k4];
            #pragma unroll
            for (int kk = 0; kk < 4; ++kk)
                *(float4*)wr[kk] = *(const float4*)&wt[(4 * k4 + kk) * WT_STRIDE + e0];
            #pragma unroll
            for (int kk = 0; kk < 4; ++kk) {
                #pragma unroll
                for (int i = 0; i < 4; ++i) {
                    acc0[i] = fmaf(xr0[kk], wr[kk][i], acc0[i]);
                    acc1[i] = fmaf(xr1[kk], wr[kk][i], acc1[i]);
                }
            }
        }
        __syncthreads();
    }

    // ---- epilogue: gather logits, top-2, softmax ----
    #pragma unroll
    for (int i = 0; i < 4; ++i) {
        logits_s[(tt0 + 0) * (NEXP + 1) + e0 + i] = acc0[i];
        logits_s[(tt0 + 1) * (NEXP + 1) + e0 + i] = acc1[i];
    }
    __syncthreads();

    if (tid < TM) {
        const int t = tid;
        float m1 = -INFINITY, m2 = -INFINITY;
        int i1 = 0, i2 = 0;
        #pragma unroll
        for (int e = 0; e < NEXP; ++e) {
            float v = logits_s[t * (NEXP + 1) + e];
            if (v > m1) { m2 = m1; i2 = i1; m1 = v; i1 = e; }
            else if (v > m2) { m2 = v; i2 = e; }
        }
        // softmax over [m1, m2], m1 >= m2
        float e2 = expf(m2 - m1);
        float denom = 1.f + e2;
        float s1 = 1.f / denom;
        float s2 = e2 / denom;
        int gt = t0 + t;
        out[gt * 2 + 0] = s1;
        out[gt * 2 + 1] = s2;
        out[2 * T_TOKENS + gt * 2 + 0] = (float)i1;
        out[2 * T_TOKENS + gt * 2 + 1] = (float)i2;
    }
}

extern "C" void kernel_launch(void* const* d_in, const int* in_sizes, int n_in,
                              void* d_out, int out_size, void* d_ws, size_t ws_size,
                              hipStream_t stream) {
    const float* x = (const float*)d_in[0];
    const float* W = (const float*)d_in[1];
    float* out = (float*)d_out;
    dim3 grid(T_TOKENS / TM);   // 512 blocks
    dim3 block(256);
    topk_router_kernel<<<grid, block, 0, stream>>>(x, W, out);
}

// Round 2
// 411.182 us; speedup vs baseline: 1.0450x; 1.0450x over previous
//
#include <hip/hip_runtime.h>
#include <math.h>

#define T_TOKENS 16384
#define NEXP     64
#define KDIM     4096
#define TM       32                 // tokens per block -> grid 512
#define KC       64                 // k per LDS chunk
#define NCHUNK   (KDIM / KC)        // 64
#define WCHUNK_B 16384              // 2(h/l) * 2(s) * 4(ntile) * 64(lane) * 16B
#define XBYTES   8192               // 2(h/l) * 2(s) * 2(mtile) * 64(lane) * 16B

typedef _Float16 f16;
typedef f16   f16x8 __attribute__((ext_vector_type(8)));
typedef float f32x4 __attribute__((ext_vector_type(4)));

__device__ __forceinline__ void load_lds16(const void* g, void* l) {
    __builtin_amdgcn_global_load_lds(
        (const __attribute__((address_space(1))) unsigned int*)g,
        (__attribute__((address_space(3))) unsigned int*)l, 16, 0, 0);
}

// ---------------------------------------------------------------------------
// Pre-kernel: W[64][4096] fp32 -> frag-linear tiled fp16 hi/lo in d_ws (1 MB).
// Layout (byte image of each KC-chunk's LDS W buffer):
//   [kc][h][s][ntile][lane][j] : off = kc*16384 + h*8192 + s*4096 + nt*1024 + lane*16 + j*2
// where expert = nt*16 + (lane&15), k = kc*64 + s*32 + (lane>>4)*8 + j.
// W is pre-scaled by 64 (w64 ~ N(0,1): keeps fp16 normal); lo scaled by 2^11.
// ---------------------------------------------------------------------------
__global__ void w_tile_kernel(const float* __restrict__ W, f16* __restrict__ wt) {
    int o = blockIdx.x * 256 + threadIdx.x;     // 524288 elements total
    int j  = o & 7;
    int ln = (o >> 3) & 63;
    int nt = (o >> 9) & 3;
    int s  = (o >> 11) & 1;
    int h  = (o >> 12) & 1;
    int kc = o >> 13;
    int e  = nt * 16 + (ln & 15);
    int k  = kc * KC + s * 32 + (ln >> 4) * 8 + j;
    float w64 = W[(size_t)e * KDIM + k] * 64.0f;
    f16 hi = (f16)w64;                                   // RNE
    f16 v  = (h == 0) ? hi : (f16)((w64 - (float)hi) * 2048.0f);  // exact residual, scaled
    wt[o] = v;
}

// ---------------------------------------------------------------------------
// Main kernel: 512 blocks x 256 thr (4 waves). Block = 32 tokens x 64 experts.
// Wave w: Mtile = w&1 (16 tokens), Ntiles = 2*(w>>1)+{0,1} (32 experts).
// Split-fp16: logit = (acc_hh + acc_lo/2048)/64.
// ---------------------------------------------------------------------------
__global__ __launch_bounds__(256, 2) void router_mfma(
    const float* __restrict__ x, const f16* __restrict__ wt,
    float* __restrict__ out)
{
    __shared__ __align__(16) unsigned char xsm[XBYTES];
    __shared__ __align__(16) unsigned char wsm[2][WCHUNK_B];   // double-buffered W
    __shared__ float logits_s[TM][NEXP + 1];

    const int tid  = threadIdx.x;
    const int wid  = tid >> 6;
    const int lane = tid & 63;
    const int t0   = blockIdx.x * TM;

    // ---- x staging mapping: thread = (token m = tid>>3, k-oct q = tid&7) ----
    // global: 2 coalesced float4 per thread; LDS: one b128 each for h and l.
    const int xm = tid >> 3, xq = tid & 7;
    const float* xg = x + (size_t)(t0 + xm) * KDIM + xq * 8;
    const int xs_s = xq >> 2, xmt = xm >> 4, xlane = (xm & 15) + 16 * (xq & 3);
    f16* const xw_h = (f16*)(xsm + 0    + xs_s * 2048 + xmt * 1024 + xlane * 16);
    f16* const xw_l = (f16*)(xsm + 4096 + xs_s * 2048 + xmt * 1024 + xlane * 16);

    // ---- compute mapping ----
    const int mt = wid & 1, nt0 = (wid >> 1) * 2;
    const unsigned char* const wtb = (const unsigned char*)wt;

    f32x4 acc_hh[2], acc_lo[2];
    #pragma unroll
    for (int t = 0; t < 2; ++t) {
        acc_hh[t] = (f32x4){0.f, 0.f, 0.f, 0.f};
        acc_lo[t] = (f32x4){0.f, 0.f, 0.f, 0.f};
    }

    // ---- prologue: x chunk 0 -> regs, W chunk 0 -> wsm[0] ----
    float4 xr0 = *(const float4*)(xg);
    float4 xr1 = *(const float4*)(xg + 4);
    #pragma unroll
    for (int cc = 0; cc < 4; ++cc)
        load_lds16(wtb + cc * 4096 + tid * 16,
                   wsm[0] + cc * 4096 + wid * 1024);

    for (int c = 0; c < NCHUNK; ++c) {
        // convert chunk-c x regs -> fp16 h/l frags in LDS
        float v[8] = {xr0.x, xr0.y, xr0.z, xr0.w, xr1.x, xr1.y, xr1.z, xr1.w};
        f16x8 hv, lv;
        #pragma unroll
        for (int j = 0; j < 8; ++j) {
            f16 h = (f16)v[j];                    // RNE; |x| <= ~6 fits fp16
            hv[j] = h;
            lv[j] = (f16)((v[j] - (float)h) * 2048.0f);  // exact residual * 2^11
        }
        *(f16x8*)xw_h = hv;
        *(f16x8*)xw_l = lv;

        __syncthreads();   // B1: x writes + W[c] DMA (drained at previous B2) visible

        // prefetch next chunk while MFMAs run; barrier B2 drains them
        if (c + 1 < NCHUNK) {
            const unsigned char* wg = wtb + (size_t)(c + 1) * WCHUNK_B;
            unsigned char* wdst = wsm[(c + 1) & 1];
            #pragma unroll
            for (int cc = 0; cc < 4; ++cc)
                load_lds16(wg + cc * 4096 + tid * 16,
                           wdst + cc * 4096 + wid * 1024);
            const float* xg2 = xg + (c + 1) * KC;
            xr0 = *(const float4*)(xg2);
            xr1 = *(const float4*)(xg2 + 4);
        }

        // ---- MFMA phase: 12 b128 frag reads + 12 MFMA per wave per chunk ----
        const unsigned char* wb = wsm[c & 1];
        #pragma unroll
        for (int s = 0; s < 2; ++s) {
            const f16x8 ah = *(const f16x8*)(xsm + 0    + s * 2048 + mt * 1024 + lane * 16);
            const f16x8 al = *(const f16x8*)(xsm + 4096 + s * 2048 + mt * 1024 + lane * 16);
            #pragma unroll
            for (int t = 0; t < 2; ++t) {
                const f16x8 bh = *(const f16x8*)(wb + 0    + s * 4096 + (nt0 + t) * 1024 + lane * 16);
                const f16x8 bl = *(const f16x8*)(wb + 8192 + s * 4096 + (nt0 + t) * 1024 + lane * 16);
                acc_hh[t] = __builtin_amdgcn_mfma_f32_16x16x32_f16(ah, bh, acc_hh[t], 0, 0, 0);
                acc_lo[t] = __builtin_amdgcn_mfma_f32_16x16x32_f16(ah, bl, acc_lo[t], 0, 0, 0);
                acc_lo[t] = __builtin_amdgcn_mfma_f32_16x16x32_f16(al, bh, acc_lo[t], 0, 0, 0);
            }
        }
        __syncthreads();   // B2: LDS consumed; drains next-chunk DMA + x loads
    }

    // ---- epilogue: C/D layout col=lane&15, row=(lane>>4)*4+reg (m89-verified) ----
    #pragma unroll
    for (int t = 0; t < 2; ++t) {
        #pragma unroll
        for (int r = 0; r < 4; ++r) {
            int token  = mt * 16 + (lane >> 4) * 4 + r;
            int expert = (nt0 + t) * 16 + (lane & 15);
            logits_s[token][expert] =
                (acc_hh[t][r] + acc_lo[t][r] * (1.0f / 2048.0f)) * (1.0f / 64.0f);
        }
    }
    __syncthreads();

    if (tid < TM) {
        const int t = tid;
        float m1 = -INFINITY, m2 = -INFINITY;
        int i1 = 0, i2 = 0;
        #pragma unroll
        for (int e = 0; e < NEXP; ++e) {
            float v = logits_s[t][e];
            if (v > m1)      { m2 = m1; i2 = i1; m1 = v; i1 = e; }
            else if (v > m2) { m2 = v; i2 = e; }
        }
        float e2 = __expf(m2 - m1);
        float denom = 1.f + e2;
        int gt = t0 + t;
        out[gt * 2 + 0] = 1.f / denom;
        out[gt * 2 + 1] = e2 / denom;
        out[2 * T_TOKENS + gt * 2 + 0] = (float)i1;
        out[2 * T_TOKENS + gt * 2 + 1] = (float)i2;
    }
}

extern "C" void kernel_launch(void* const* d_in, const int* in_sizes, int n_in,
                              void* d_out, int out_size, void* d_ws, size_t ws_size,
                              hipStream_t stream) {
    const float* x = (const float*)d_in[0];
    const float* W = (const float*)d_in[1];
    f16* wt = (f16*)d_ws;              // needs 1 MB of scratch

    // W -> tiled fp16 hi/lo (re-run every call: ws is re-poisoned by harness)
    w_tile_kernel<<<2048, 256, 0, stream>>>(W, wt);
    router_mfma<<<T_TOKENS / TM, 256, 0, stream>>>(x, wt, (float*)d_out);
}

// Round 4
// 396.654 us; speedup vs baseline: 1.0833x; 1.0366x over previous
//
#include <hip/hip_runtime.h>
#include <math.h>

#define T_TOKENS 16384
#define NEXP     64
#define KDIM     4096
#define TM       16                  // tokens per block -> grid 1024
#define ROUNDS   16                  // per-wave K/4=1024, KC=64 per round

typedef _Float16 f16;
typedef f16   f16x2 __attribute__((ext_vector_type(2)));
typedef f16   f16x8 __attribute__((ext_vector_type(8)));
typedef float f32x4 __attribute__((ext_vector_type(4)));

// XOR swizzle on 16B-unit LDS offsets: banks get oct(2b) + k32(1b) mixed in.
__device__ __forceinline__ int swz(int o) {
    return o ^ ((o >> 4) & 3) ^ (((o >> 6) & 1) << 2);
}

// ---------------------------------------------------------------------------
// Pre-kernel: W[64][4096] fp32 -> frag-linear fp16 hi/lo in d_ws (1 MB).
// uint4 frag index = ((kg32*4 + nt)*2 + fmt)*64 + lane ; element j in [0,8).
// expert = nt*16 + (lane&15), k = kg32*32 + (lane>>4)*8 + j.  W pre-scaled x64.
// ---------------------------------------------------------------------------
__global__ void w_tile_kernel(const float* __restrict__ W, f16* __restrict__ wt) {
    int o = blockIdx.x * 256 + threadIdx.x;       // 524288 f16 elements
    int j    = o & 7;
    int lane = (o >> 3) & 63;
    int fmt  = (o >> 9) & 1;
    int nt   = (o >> 10) & 3;
    int kg32 = o >> 12;                           // 0..127
    int e = nt * 16 + (lane & 15);
    int k = kg32 * 32 + (lane >> 4) * 8 + j;
    float w64 = W[(size_t)e * KDIM + k] * 64.0f;
    f16 hi = (f16)w64;                            // RNE
    f16 v  = (fmt == 0) ? hi : (f16)((w64 - (float)hi) * 2048.0f);
    wt[o] = v;
}

// split 8 fp32 -> packed fp16 hi (uint4) and lo*2^11 (uint4)
__device__ __forceinline__ void split8(const float v[8], uint4* ho, uint4* lo) {
    unsigned hu[4], lu[4];
    #pragma unroll
    for (int p = 0; p < 4; ++p) {
        f16x2 h2, l2;
#if __has_builtin(__builtin_amdgcn_cvt_pkrtz)
        h2 = __builtin_bit_cast(f16x2, __builtin_amdgcn_cvt_pkrtz(v[2*p], v[2*p+1]));
#else
        h2.x = (f16)v[2*p]; h2.y = (f16)v[2*p+1];
#endif
        float r0 = (v[2*p]   - (float)h2.x) * 2048.0f;
        float r1 = (v[2*p+1] - (float)h2.y) * 2048.0f;
#if __has_builtin(__builtin_amdgcn_cvt_pkrtz)
        l2 = __builtin_bit_cast(f16x2, __builtin_amdgcn_cvt_pkrtz(r0, r1));
#else
        l2.x = (f16)r0; l2.y = (f16)r1;
#endif
        hu[p] = __builtin_bit_cast(unsigned, h2);
        lu[p] = __builtin_bit_cast(unsigned, l2);
    }
    *ho = make_uint4(hu[0], hu[1], hu[2], hu[3]);
    *lo = make_uint4(lu[0], lu[1], lu[2], lu[3]);
}

__device__ __forceinline__ f16x8 asf16x8(uint4 u) {
    return __builtin_bit_cast(f16x8, u);
}

// ---------------------------------------------------------------------------
// Main: 1024 blocks x 256 thr (4 waves). Block = 16 tokens x 64 experts.
// Wave wid = K-quarter (1024 k). W frags come straight from global (L1/L2);
// LDS only transposes x into A-frag layout (swizzled, conflict-free).
// logit*64 = acc_hh + acc_lo/2048  (W was pre-scaled by 64).
// ---------------------------------------------------------------------------
__global__ __launch_bounds__(256, 3) void router_mfma(
    const float* __restrict__ x, const uint4* __restrict__ wt,
    float* __restrict__ out)
{
    __shared__ __align__(16) unsigned char xs[16384];   // 2 fmt x 4 w'' x 2 k32 x 64 x 16B
    __shared__ float partial[4][TM][68];                // +pad: conflict-free

    const int tid  = threadIdx.x;
    const int wid  = tid >> 6;
    const int lane = tid & 63;
    const int t0   = blockIdx.x * TM;

    // ---- x staging mapping: slot s in {0,1}: token = s*8 + (tid>>5), oct8 = tid&31
    const int tok_hi = tid >> 5;              // 0..7
    const int oct8   = tid & 31;
    const int xw     = oct8 >> 3;             // staging w'' (K-quarter)
    const int xk32   = (oct8 >> 2) & 1;
    const int xoct   = oct8 & 3;
    const int koff   = (oct8 & 7) * 8;        // k within the 64-k round slice
    const float* xrow[2] = {
        x + (size_t)(t0 + 0 + tok_hi) * KDIM + xw * 1024 + koff,
        x + (size_t)(t0 + 8 + tok_hi) * KDIM + xw * 1024 + koff
    };
    int owr[2];                               // swizzled 16B-unit write offsets (h)
    #pragma unroll
    for (int s = 0; s < 2; ++s) {
        int lane_f = (s * 8 + tok_hi) + 16 * xoct;
        owr[s] = swz(xw * 128 + xk32 * 64 + lane_f);
    }

    // ---- A-frag read offsets (swizzled), per k32 step ----
    int ord[2];
    #pragma unroll
    for (int s = 0; s < 2; ++s) ord[s] = swz(wid * 128 + s * 64 + lane);

    f32x4 acc_hh[4], acc_lo[4];
    #pragma unroll
    for (int nt = 0; nt < 4; ++nt) {
        acc_hh[nt] = (f32x4){0.f, 0.f, 0.f, 0.f};
        acc_lo[nt] = (f32x4){0.f, 0.f, 0.f, 0.f};
    }

    // prologue: x round 0 -> regs
    float4 xc[2][2], xn[2][2];
    #pragma unroll
    for (int s = 0; s < 2; ++s) {
        xc[s][0] = *(const float4*)(xrow[s]);
        xc[s][1] = *(const float4*)(xrow[s] + 4);
    }

    for (int r = 0; r < ROUNDS; ++r) {
        // ---- convert + write x_r into A-frag LDS (4x b128, swizzled) ----
        #pragma unroll
        for (int s = 0; s < 2; ++s) {
            float v[8] = { xc[s][0].x, xc[s][0].y, xc[s][0].z, xc[s][0].w,
                           xc[s][1].x, xc[s][1].y, xc[s][1].z, xc[s][1].w };
            uint4 ho, lo;
            split8(v, &ho, &lo);
            *(uint4*)(xs + owr[s] * 16)         = ho;
            *(uint4*)(xs + (owr[s] + 512) * 16) = lo;
        }
        __syncthreads();   // B1: xs ready

        // ---- issue W-frag loads (global, coalesced, L1/L2) + x prefetch ----
        const uint4* wfrag = wt + ((size_t)(wid * 32 + r * 2) * 512) + lane;
        uint4 b0[8], b1[8];
        #pragma unroll
        for (int nt = 0; nt < 4; ++nt) {
            b0[nt*2]   = wfrag[nt * 128];
            b0[nt*2+1] = wfrag[nt * 128 + 64];
        }
        #pragma unroll
        for (int nt = 0; nt < 4; ++nt) {
            b1[nt*2]   = wfrag[512 + nt * 128];
            b1[nt*2+1] = wfrag[512 + nt * 128 + 64];
        }
        if (r + 1 < ROUNDS) {
            #pragma unroll
            for (int s = 0; s < 2; ++s) {
                xn[s][0] = *(const float4*)(xrow[s] + (r + 1) * 64);
                xn[s][1] = *(const float4*)(xrow[s] + (r + 1) * 64 + 4);
            }
        }

        // ---- MFMA: 2 k32 steps x 4 ntiles x 3 passes ----
        #pragma unroll
        for (int s = 0; s < 2; ++s) {
            f16x8 ah = asf16x8(*(const uint4*)(xs + ord[s] * 16));
            f16x8 al = asf16x8(*(const uint4*)(xs + (ord[s] + 512) * 16));
            uint4* b = (s == 0) ? b0 : b1;
            #pragma unroll
            for (int nt = 0; nt < 4; ++nt) {
                f16x8 bh = asf16x8(b[nt*2]);
                f16x8 bl = asf16x8(b[nt*2+1]);
                acc_hh[nt] = __builtin_amdgcn_mfma_f32_16x16x32_f16(ah, bh, acc_hh[nt], 0, 0, 0);
                acc_lo[nt] = __builtin_amdgcn_mfma_f32_16x16x32_f16(ah, bl, acc_lo[nt], 0, 0, 0);
                acc_lo[nt] = __builtin_amdgcn_mfma_f32_16x16x32_f16(al, bh, acc_lo[nt], 0, 0, 0);
            }
        }
        __syncthreads();   // B2: xs consumed; drains x(r+1) loads
        #pragma unroll
        for (int s = 0; s < 2; ++s) { xc[s][0] = xn[s][0]; xc[s][1] = xn[s][1]; }
    }

    // ---- epilogue: per-wave partial logits (x64-scaled), cross-wave sum, top-2 ----
    #pragma unroll
    for (int nt = 0; nt < 4; ++nt) {
        #pragma unroll
        for (int rr = 0; rr < 4; ++rr) {
            int token = (lane >> 4) * 4 + rr;          // C/D: col=lane&15,row=(lane>>4)*4+reg
            int e     = nt * 16 + (lane & 15);
            partial[wid][token][e] = acc_hh[nt][rr] + acc_lo[nt][rr] * (1.0f / 2048.0f);
        }
    }
    __syncthreads();

    if (tid < TM) {
        const int t = tid;
        float m1 = -INFINITY, m2 = -INFINITY;
        int i1 = 0, i2 = 0;
        for (int e = 0; e < NEXP; ++e) {
            float v = partial[0][t][e] + partial[1][t][e]
                    + partial[2][t][e] + partial[3][t][e];
            if (v > m1)      { m2 = m1; i2 = i1; m1 = v; i1 = e; }
            else if (v > m2) { m2 = v; i2 = e; }
        }
        float e2 = __expf((m2 - m1) * (1.0f / 64.0f));  // undo x64 W scale
        float denom = 1.f + e2;
        int gt = t0 + t;
        out[gt * 2 + 0] = 1.f / denom;
        out[gt * 2 + 1] = e2 / denom;
        out[2 * T_TOKENS + gt * 2 + 0] = (float)i1;
        out[2 * T_TOKENS + gt * 2 + 1] = (float)i2;
    }
}

extern "C" void kernel_launch(void* const* d_in, const int* in_sizes, int n_in,
                              void* d_out, int out_size, void* d_ws, size_t ws_size,
                              hipStream_t stream) {
    const float* x = (const float*)d_in[0];
    const float* W = (const float*)d_in[1];
    f16* wt = (f16*)d_ws;   // 1 MB scratch, rebuilt every call (ws re-poisoned)

    w_tile_kernel<<<2048, 256, 0, stream>>>(W, wt);
    router_mfma<<<T_TOKENS / TM, 256, 0, stream>>>(x, (const uint4*)wt, (float*)d_out);
}